// Round 5
// baseline (719.069 us; speedup 1.0000x reference)
//
#include <hip/hip_runtime.h>
#include <math.h>

#define PI_F 3.14159265358979323846f

// FFT LDS padding: +1 complex slot every 16 -> breaks radix-4's power-of-2
// write strides (16-way conflicts) down to <=4-way while keeping stride-1
// runs contiguous within 16-blocks.
#define FI(i) ((i) + ((i) >> 4))
#define CSTRIDE 544  // padded per-column stride: 512 + 32

__device__ inline float2 cmulf(float2 a, float2 b) {
    return make_float2(a.x * b.x - a.y * b.y, a.x * b.y + a.y * b.x);
}
__device__ inline float2 cadd(float2 a, float2 b) { return make_float2(a.x + b.x, a.y + b.y); }
__device__ inline float2 csub(float2 a, float2 b) { return make_float2(a.x - b.x, a.y - b.y); }

// Complex MAC: a += w * v
__device__ inline void cmac(float2& a, float2 w, float2 v) {
    a.x = fmaf(w.x, v.x, a.x);
    a.x = fmaf(-w.y, v.y, a.x);
    a.y = fmaf(w.x, v.y, a.y);
    a.y = fmaf(w.y, v.x, a.y);
}

// Bijective chunked XCD remap (grid % 8 == 0): hardware bids with equal
// (bid&7) — same XCD under round-robin dispatch — get CONSECUTIVE logical
// indices, so line-sharing neighbor blocks hit the same L2.
__device__ inline int xcd_remap(int bid, int q) {
    return (bid & 7) * q + (bid >> 3);
}

// tbl[k] = exp(-2*pi*i*k/512), k in [0,128) — only w1 twiddles needed;
// w2/w3 are squared/cubed in registers.
__device__ inline void build_tbl128(float2* tbl, int tid) {
    if (tid < 128) {
        float ang = -2.0f * PI_F * (float)tid * (1.0f / 512.0f);
        tbl[tid] = make_float2(cosf(ang), sinf(ang));
    }
}

// 512-point Stockham FFT, radix-4 x4 + radix-2 final (5 stages, 5 barriers),
// over NCOLS interleaved transforms. Data at a[col*CSTRIDE + FI(i)];
// b is ping-pong. 256 threads.
template <int NCOLS>
__device__ inline float2* fft512_r4(float2* a, float2* b, const float2* tbl, int tid, bool inv) {
    const int bf = tid & 127;  // butterfly index within a column
    const int cp = tid >> 7;   // column parity this thread covers
#pragma unroll
    for (int st = 0; st < 4; ++st) {
        const int slog = 2 * st;
        const int s = 1 << slog;
        const int p = bf >> slog;
        const int q = bf & (s - 1);
        float2 w1 = tbl[p << slog];
        if (inv) w1.y = -w1.y;
        const float2 w2 = cmulf(w1, w1);
        const float2 w3 = cmulf(w2, w1);
        const int i0 = bf;                     // q + s*p
        const int ob = q + (p << (slog + 2));  // q + 4*s*p
#pragma unroll
        for (int t = 0; t < NCOLS / 2; ++t) {
            const int cc = cp + 2 * t;
            const float2* ac = a + cc * CSTRIDE;
            float2* bc = b + cc * CSTRIDE;
            float2 A = ac[FI(i0)];
            float2 B = ac[FI(i0 + 128)];
            float2 C = ac[FI(i0 + 256)];
            float2 D = ac[FI(i0 + 384)];
            float2 apc = cadd(A, C), amc = csub(A, C);
            float2 bpd = cadd(B, D), bmd = csub(B, D);
            float2 jb = make_float2(-bmd.y, bmd.x);  // i*(B-D)
            if (inv) { jb.x = -jb.x; jb.y = -jb.y; }
            bc[FI(ob)]           = cadd(apc, bpd);
            bc[FI(ob + s)]       = cmulf(csub(amc, jb), w1);
            bc[FI(ob + 2 * s)]   = cmulf(csub(apc, bpd), w2);
            bc[FI(ob + 3 * s)]   = cmulf(cadd(amc, jb), w3);
        }
        __syncthreads();
        float2* tmp = a; a = b; b = tmp;
    }
    // final radix-2 stage: n=2, s=256, twiddle-free
    {
#pragma unroll
        for (int cc = 0; cc < NCOLS; ++cc) {
            const float2* ac = a + cc * CSTRIDE;
            float2* bc = b + cc * CSTRIDE;
            float2 A = ac[FI(tid)];
            float2 B = ac[FI(tid + 256)];
            bc[FI(tid)]       = cadd(A, B);
            bc[FI(tid + 256)] = csub(A, B);
        }
        __syncthreads();
        float2* tmp = a; a = b; b = tmp;
    }
    return a;
}

// K1: real FFT of rows of x, 4 rows per block. Output TRANSPOSED:
// GT[nc][v][h] so K2 reads coalesced. Each thread packs its 4 h-values
// (contiguous in memory) into two 16-B stores at stride 4096; XCD remap
// groups the 4 h-blocks that fill each 128-B line onto one L2.
__global__ __launch_bounds__(256) void k_row_rfft(const float* __restrict__ x,
                                                  float2* __restrict__ GT) {
    __shared__ float2 b0[4 * CSTRIDE], b1[4 * CSTRIDE], tbl[128];
    int tid = threadIdx.x;
    int l = xcd_remap(blockIdx.x, 2048);  // grid = 16384
    int nc = l >> 7;
    int h0 = (l & 127) * 4;
    build_tbl128(tbl, tid);
    const float4* xr = (const float4*)(x + ((size_t)nc * 512 + h0) * 512);
#pragma unroll
    for (int j = 0; j < 2; ++j) {
        int t4 = tid + 256 * j;  // float4 index in [0,512)
        float4 v = xr[t4];
        int e = t4 * 4;          // element index in [0,2048)
        int k = e >> 9, i = e & 511;
        float2* dst = b0 + k * CSTRIDE + FI(i);
        dst[0] = make_float2(v.x, 0.0f);
        dst[1] = make_float2(v.y, 0.0f);
        dst[2] = make_float2(v.z, 0.0f);
        dst[3] = make_float2(v.w, 0.0f);
    }
    __syncthreads();
    float2* res = fft512_r4<4>(b0, b1, tbl, tid, false);
    // transpose-write: thread tid owns v=tid (tid 0 also v=256); 4 h contiguous
    {
        float2* g = GT + ((size_t)nc * 257 + tid) * 512 + h0;
        float4* g4 = (float4*)g;
        float2 r0 = res[0 * CSTRIDE + FI(tid)];
        float2 r1 = res[1 * CSTRIDE + FI(tid)];
        float2 r2 = res[2 * CSTRIDE + FI(tid)];
        float2 r3 = res[3 * CSTRIDE + FI(tid)];
        g4[0] = make_float4(r0.x, r0.y, r1.x, r1.y);
        g4[1] = make_float4(r2.x, r2.y, r3.x, r3.y);
        if (tid == 0) {
            float2* gn = GT + ((size_t)nc * 257 + 256) * 512 + h0;
            float4* gn4 = (float4*)gn;
            float2 s0 = res[0 * CSTRIDE + FI(256)];
            float2 s1 = res[1 * CSTRIDE + FI(256)];
            float2 s2 = res[2 * CSTRIDE + FI(256)];
            float2 s3 = res[3 * CSTRIDE + FI(256)];
            gn4[0] = make_float4(s0.x, s0.y, s1.x, s1.y);
            gn4[1] = make_float4(s2.x, s2.y, s3.x, s3.y);
        }
    }
}

// K2: FFT along h for 4 adjacent columns v0..v0+3. Reads GT COALESCED
// (lanes vary h). XCD-chunk swizzled so v-group neighbors share L2.
__global__ __launch_bounds__(256) void k_col_fft(const float2* __restrict__ GT,
                                                 float2* __restrict__ XT) {
    __shared__ float2 b0[4 * CSTRIDE], b1[4 * CSTRIDE], tbl[128];
    int tid = threadIdx.x;
    int l = xcd_remap(blockIdx.x, 1040);  // grid = 8320
    int nc = l / 65;
    int v0 = (l % 65) * 4;
    build_tbl128(tbl, tid);
#pragma unroll
    for (int i = 0; i < 8; ++i) {
        int e = tid + 256 * i;
        int k = e >> 9, h = e & 511;
        int v = v0 + k;
        float2 val = make_float2(0.0f, 0.0f);
        if (v < 257) val = GT[((size_t)nc * 257 + v) * 512 + h];
        b0[k * CSTRIDE + FI(h)] = val;
    }
    __syncthreads();
    float2* res = fft512_r4<4>(b0, b1, tbl, tid, false);
#pragma unroll
    for (int k = 0; k < 4; ++k) {
        int v = v0 + k;
        if (v < 257) {
            float2* dst = XT + ((size_t)nc * 257 + v) * 512;
            dst[tid]       = res[k * CSTRIDE + FI(tid)];
            dst[tid + 256] = res[k * CSTRIDE + FI(tid + 256)];
        }
    }
}

// K3: complex 3x3 conv, 16->16 channels, zero padding, on the half-spectrum.
// o is wave-uniform (wave wv owns o = 4*wv..4*wv+3); lane = u. Weights via
// scalar loads; X tile in linear LDS, contiguous lane-indexed ds_read_b64.
// (4-fma cmac form — measured faster than Gauss 3-mult: the extra scalar
// weight stream cost more in SMEM stalls than the saved FMAs.)
__global__ __launch_bounds__(256, 6) void k_conv(const float2* __restrict__ XT,
                                                 float2* __restrict__ YT,
                                                 const float* __restrict__ wr,
                                                 const float* __restrict__ wi,
                                                 const float* __restrict__ br,
                                                 const float* __restrict__ bi) {
    __shared__ float2 Xs[16 * 3 * 66];  // [c][dv][uu], linear, no padding
    int tid = threadIdx.x;
    int bid = blockIdx.x;
    int ut = bid & 7;
    int rest = bid >> 3;
    int v = rest % 257;
    int n = rest / 257;
    int u0 = ut * 64;

    for (int l = tid; l < 3168; l += 256) {
        int c = l / 198;
        int rem = l - c * 198;
        int dv = rem / 66;
        int uu = rem - dv * 66;
        int vg = v - 1 + dv;
        int ug = u0 - 1 + uu;
        float2 val = make_float2(0.0f, 0.0f);
        if (vg >= 0 && vg < 257 && ug >= 0 && ug < 512)
            val = XT[(((size_t)n * 16 + c) * 257 + vg) * 512 + ug];
        Xs[l] = val;
    }
    __syncthreads();

    int lane = tid & 63;
    int wv = __builtin_amdgcn_readfirstlane(tid >> 6);
    int o0 = wv * 4;

    float2 acc[4];
#pragma unroll
    for (int oo = 0; oo < 4; ++oo)
        acc[oo] = make_float2(br[o0 + oo], bi[o0 + oo]);

    for (int c = 0; c < 16; ++c) {
        float2 xv[3][3];
#pragma unroll
        for (int dv = 0; dv < 3; ++dv) {
            const float2* row = &Xs[(c * 3 + dv) * 66];
            xv[dv][0] = row[lane];
            xv[dv][1] = row[lane + 1];
            xv[dv][2] = row[lane + 2];
        }
#pragma unroll
        for (int oo = 0; oo < 4; ++oo) {
            const float* wrp = wr + ((size_t)(c * 16 + o0 + oo)) * 9;
            const float* wip = wi + ((size_t)(c * 16 + o0 + oo)) * 9;
            float wre[9], wim[9];
#pragma unroll
            for (int t = 0; t < 9; ++t) { wre[t] = wrp[t]; wim[t] = wip[t]; }
#pragma unroll
            for (int dv = 0; dv < 3; ++dv) {
                int kw = 2 - dv;
#pragma unroll
                for (int kh = 0; kh < 3; ++kh) {
                    int t = kh * 3 + kw;
                    float2 w = make_float2(wre[t], wim[t]);
                    cmac(acc[oo], w, xv[dv][2 - kh]);
                }
            }
        }
    }

#pragma unroll
    for (int oo = 0; oo < 4; ++oo) {
        YT[(((size_t)n * 16 + o0 + oo) * 257 + v) * 512 + u0 + lane] = acc[oo];
    }
}

// K4: inverse FFT along u (scale 1/512) for 4 columns. Reads YT coalesced;
// writes TRANSPOSED ZTT[no][u][v] (4 contiguous-v float2 stores per thread,
// stride 2056) so K5 reads coalesced. XCD remap groups v-neighbors.
__global__ __launch_bounds__(256) void k_col_ifft(const float2* __restrict__ YT,
                                                  float2* __restrict__ ZTT) {
    __shared__ float2 b0[4 * CSTRIDE], b1[4 * CSTRIDE], tbl[128];
    int tid = threadIdx.x;
    int l = xcd_remap(blockIdx.x, 1040);  // grid = 8320
    int no = l / 65;
    int v0 = (l % 65) * 4;
    build_tbl128(tbl, tid);
#pragma unroll
    for (int k = 0; k < 4; ++k) {
        int v = v0 + k;
        const float2* src = YT + ((size_t)no * 257 + (v < 257 ? v : 256)) * 512;
        b0[k * CSTRIDE + FI(tid)]       = src[tid];
        b0[k * CSTRIDE + FI(tid + 256)] = src[tid + 256];
    }
    __syncthreads();
    float2* res = fft512_r4<4>(b0, b1, tbl, tid, true);
    const float sc = 1.0f / 512.0f;
    float2* d0 = ZTT + ((size_t)no * 512 + tid) * 257 + v0;
    float2* d1 = ZTT + ((size_t)no * 512 + tid + 256) * 257 + v0;
#pragma unroll
    for (int k = 0; k < 4; ++k) {
        if (v0 + k < 257) {
            float2 r0 = res[k * CSTRIDE + FI(tid)];
            float2 r1 = res[k * CSTRIDE + FI(tid + 256)];
            d0[k] = make_float2(r0.x * sc, r0.y * sc);
            d1[k] = make_float2(r1.x * sc, r1.y * sc);
        }
    }
}

// K5: irfft along v for 4 rows h0..h0+3 (imag of DC/Nyquist ignored).
// Reads ZTT COALESCED (lanes vary v). XCD-chunk swizzled.
__global__ __launch_bounds__(256) void k_row_irfft(const float2* __restrict__ ZTT,
                                                   float* __restrict__ out) {
    __shared__ float2 b0[4 * CSTRIDE], b1[4 * CSTRIDE], tbl[128];
    int tid = threadIdx.x;
    int l = xcd_remap(blockIdx.x, 2048);  // grid = 16384
    int no = l >> 7;
    int h0 = (l & 127) * 4;
    build_tbl128(tbl, tid);
#pragma unroll
    for (int k = 0; k < 4; ++k) {
        const float2* src = ZTT + ((size_t)no * 512 + h0 + k) * 257;
        float2 val = src[tid];
        if (tid == 0) val.y = 0.0f;  // DC imag
        b0[k * CSTRIDE + FI(tid)] = val;
        if (tid == 0) {
            float2 vn = src[256];
            vn.y = 0.0f;             // Nyquist imag
            b0[k * CSTRIDE + FI(256)] = vn;
        }
    }
    __syncthreads();
#pragma unroll
    for (int i = 0; i < 4; ++i) {
        int e = tid + 256 * i;
        if (e < 1020) {
            int k = e & 3, vv = 257 + (e >> 2);
            float2 s = b0[k * CSTRIDE + FI(512 - vv)];
            b0[k * CSTRIDE + FI(vv)] = make_float2(s.x, -s.y);
        }
    }
    __syncthreads();
    float2* res = fft512_r4<4>(b0, b1, tbl, tid, true);
    const float sc = 1.0f / 512.0f;
#pragma unroll
    for (int k = 0; k < 4; ++k) {
        float* dst = out + ((size_t)no * 512 + h0 + k) * 512;
        dst[tid]       = res[k * CSTRIDE + FI(tid)].x * sc;
        dst[tid + 256] = res[k * CSTRIDE + FI(tid + 256)].x * sc;
    }
}

extern "C" void kernel_launch(void* const* d_in, const int* in_sizes, int n_in,
                              void* d_out, int out_size, void* d_ws, size_t ws_size,
                              hipStream_t stream) {
    const float* x  = (const float*)d_in[0];
    const float* wr = (const float*)d_in[1];
    const float* wi = (const float*)d_in[2];
    const float* br = (const float*)d_in[3];
    const float* bi = (const float*)d_in[4];
    float* out = (float*)d_out;

    const size_t bufElems = (size_t)128 * 257 * 512;  // complex elements
    float2* A = (float2*)d_ws;
    float2* B = A + bufElems;

    k_row_rfft<<<128 * 128, 256, 0, stream>>>(x, A);                 // x -> GT (A)
    k_col_fft<<<128 * 65, 256, 0, stream>>>(A, B);                   // GT -> XT (B)
    k_conv<<<8 * 257 * 8, 256, 0, stream>>>(B, A, wr, wi, br, bi);   // XT -> YT (A)
    k_col_ifft<<<128 * 65, 256, 0, stream>>>(A, B);                  // YT -> ZTT (B)
    k_row_irfft<<<128 * 128, 256, 0, stream>>>(B, out);              // ZTT -> out
}

// Round 6
// 674.632 us; speedup vs baseline: 1.0659x; 1.0659x over previous
//
#include <hip/hip_runtime.h>
#include <math.h>

#define PI_F 3.14159265358979323846f

// FFT LDS padding: +1 complex slot every 16 -> breaks radix-4's power-of-2
// write strides (16-way conflicts) down to <=4-way while keeping stride-1
// runs contiguous within 16-blocks.
#define FI(i) ((i) + ((i) >> 4))
#define CSTRIDE 544  // padded per-column stride: 512 + 32

__device__ inline float2 cmulf(float2 a, float2 b) {
    return make_float2(a.x * b.x - a.y * b.y, a.x * b.y + a.y * b.x);
}
__device__ inline float2 cadd(float2 a, float2 b) { return make_float2(a.x + b.x, a.y + b.y); }
__device__ inline float2 csub(float2 a, float2 b) { return make_float2(a.x - b.x, a.y - b.y); }

// Complex MAC: a += w * v
__device__ inline void cmac(float2& a, float2 w, float2 v) {
    a.x = fmaf(w.x, v.x, a.x);
    a.x = fmaf(-w.y, v.y, a.x);
    a.y = fmaf(w.x, v.y, a.y);
    a.y = fmaf(w.y, v.x, a.y);
}

// Bijective chunked XCD remap (grid % 8 == 0): hardware bids with equal
// (bid&7) — same XCD under round-robin dispatch — get CONSECUTIVE logical
// indices, so line-sharing neighbor blocks hit the same L2.
__device__ inline int xcd_remap(int bid, int q) {
    return (bid & 7) * q + (bid >> 3);
}

// tbl[k] = exp(-2*pi*i*k/512), k in [0,128) — only w1 twiddles needed;
// w2/w3 are squared/cubed in registers.
__device__ inline void build_tbl128(float2* tbl, int tid) {
    if (tid < 128) {
        float ang = -2.0f * PI_F * (float)tid * (1.0f / 512.0f);
        tbl[tid] = make_float2(cosf(ang), sinf(ang));
    }
}

// 512-point Stockham FFT, radix-4 x4 + radix-2 final (5 stages, 5 barriers),
// over NCOLS interleaved transforms. Data at a[col*CSTRIDE + FI(i)];
// b is ping-pong. 256 threads.
template <int NCOLS>
__device__ inline float2* fft512_r4(float2* a, float2* b, const float2* tbl, int tid, bool inv) {
    const int bf = tid & 127;  // butterfly index within a column
    const int cp = tid >> 7;   // column parity this thread covers
#pragma unroll
    for (int st = 0; st < 4; ++st) {
        const int slog = 2 * st;
        const int s = 1 << slog;
        const int p = bf >> slog;
        const int q = bf & (s - 1);
        float2 w1 = tbl[p << slog];
        if (inv) w1.y = -w1.y;
        const float2 w2 = cmulf(w1, w1);
        const float2 w3 = cmulf(w2, w1);
        const int i0 = bf;                     // q + s*p
        const int ob = q + (p << (slog + 2));  // q + 4*s*p
#pragma unroll
        for (int t = 0; t < NCOLS / 2; ++t) {
            const int cc = cp + 2 * t;
            const float2* ac = a + cc * CSTRIDE;
            float2* bc = b + cc * CSTRIDE;
            float2 A = ac[FI(i0)];
            float2 B = ac[FI(i0 + 128)];
            float2 C = ac[FI(i0 + 256)];
            float2 D = ac[FI(i0 + 384)];
            float2 apc = cadd(A, C), amc = csub(A, C);
            float2 bpd = cadd(B, D), bmd = csub(B, D);
            float2 jb = make_float2(-bmd.y, bmd.x);  // i*(B-D)
            if (inv) { jb.x = -jb.x; jb.y = -jb.y; }
            bc[FI(ob)]           = cadd(apc, bpd);
            bc[FI(ob + s)]       = cmulf(csub(amc, jb), w1);
            bc[FI(ob + 2 * s)]   = cmulf(csub(apc, bpd), w2);
            bc[FI(ob + 3 * s)]   = cmulf(cadd(amc, jb), w3);
        }
        __syncthreads();
        float2* tmp = a; a = b; b = tmp;
    }
    // final radix-2 stage: n=2, s=256, twiddle-free
    {
#pragma unroll
        for (int cc = 0; cc < NCOLS; ++cc) {
            const float2* ac = a + cc * CSTRIDE;
            float2* bc = b + cc * CSTRIDE;
            float2 A = ac[FI(tid)];
            float2 B = ac[FI(tid + 256)];
            bc[FI(tid)]       = cadd(A, B);
            bc[FI(tid + 256)] = csub(A, B);
        }
        __syncthreads();
        float2* tmp = a; a = b; b = tmp;
    }
    return a;
}

// K1: real FFT of rows of x, 4 rows per block. (round-3 layout: G[row][v],
// coalesced 2048-B row writes — measured best.)
__global__ __launch_bounds__(256) void k_row_rfft(const float* __restrict__ x,
                                                  float2* __restrict__ G) {
    __shared__ float2 b0[4 * CSTRIDE], b1[4 * CSTRIDE], tbl[128];
    int tid = threadIdx.x;
    int nc = blockIdx.x >> 7;
    int h0 = (blockIdx.x & 127) * 4;
    build_tbl128(tbl, tid);
    const float4* xr = (const float4*)(x + ((size_t)nc * 512 + h0) * 512);
#pragma unroll
    for (int j = 0; j < 2; ++j) {
        int t4 = tid + 256 * j;  // float4 index in [0,512)
        float4 v = xr[t4];
        int e = t4 * 4;          // element index in [0,2048)
        int k = e >> 9, i = e & 511;
        float2* dst = b0 + k * CSTRIDE + FI(i);
        dst[0] = make_float2(v.x, 0.0f);
        dst[1] = make_float2(v.y, 0.0f);
        dst[2] = make_float2(v.z, 0.0f);
        dst[3] = make_float2(v.w, 0.0f);
    }
    __syncthreads();
    float2* res = fft512_r4<4>(b0, b1, tbl, tid, false);
#pragma unroll
    for (int k = 0; k < 4; ++k) {
        float2* g = G + ((size_t)(nc * 512 + h0 + k)) * 257;
        g[tid] = res[k * CSTRIDE + FI(tid)];
        if (tid == 0) g[256] = res[k * CSTRIDE + FI(256)];
    }
}

// K2: FFT along h for 4 adjacent columns v0..v0+3. XCD-chunk swizzled so
// v-group neighbors (which share 128-B lines of G) run on the same XCD.
__global__ __launch_bounds__(256) void k_col_fft(const float2* __restrict__ G,
                                                 float2* __restrict__ XT) {
    __shared__ float2 b0[4 * CSTRIDE], b1[4 * CSTRIDE], tbl[128];
    int tid = threadIdx.x;
    int l = xcd_remap(blockIdx.x, 1040);  // grid = 8320
    int nc = l / 65;
    int v0 = (l % 65) * 4;
    build_tbl128(tbl, tid);
#pragma unroll
    for (int i = 0; i < 8; ++i) {
        int e = tid + 256 * i;
        int k = e & 3, h = e >> 2;
        int v = v0 + k;
        float2 val = make_float2(0.0f, 0.0f);
        if (v < 257) val = G[((size_t)nc * 512 + h) * 257 + v];
        b0[k * CSTRIDE + FI(h)] = val;
    }
    __syncthreads();
    float2* res = fft512_r4<4>(b0, b1, tbl, tid, false);
#pragma unroll
    for (int k = 0; k < 4; ++k) {
        int v = v0 + k;
        if (v < 257) {
            float2* dst = XT + ((size_t)nc * 257 + v) * 512;
            dst[tid]       = res[k * CSTRIDE + FI(tid)];
            dst[tid + 256] = res[k * CSTRIDE + FI(tid + 256)];
        }
    }
}

// K3: complex 3x3 conv, 16->16 channels, zero padding, on the half-spectrum.
// V-PAIR TILING: each block computes a 64-u x 2-v output tile (v0, v0+1).
// The two v-windows share 2 of 3 halo rows -> per-output LDS reads -33%,
// per-output scalar weight traffic -50%, per-output staging -33%.
// o is wave-uniform (wave wv owns o = 4*wv..4*wv+3); lane = u.
__global__ __launch_bounds__(256, 4) void k_conv(const float2* __restrict__ XT,
                                                 float2* __restrict__ YT,
                                                 const float* __restrict__ wr,
                                                 const float* __restrict__ wi,
                                                 const float* __restrict__ br,
                                                 const float* __restrict__ bi) {
    __shared__ float2 Xs[16 * 4 * 66];  // [c][dvr][uu]; vg = v0-1+dvr, dvr in [0,4)
    int tid = threadIdx.x;
    int bid = blockIdx.x;
    int ut = bid & 7;
    int rest = bid >> 3;
    int vt = rest % 129;   // v-tile: covers v0 = 2*vt and v0+1
    int n = rest / 129;
    int u0 = ut * 64;
    int v0 = vt * 2;

    for (int l = tid; l < 4224; l += 256) {
        int c = l / 264;
        int rem = l - c * 264;
        int dvr = rem / 66;
        int uu = rem - dvr * 66;
        int vg = v0 - 1 + dvr;
        int ug = u0 - 1 + uu;
        float2 val = make_float2(0.0f, 0.0f);
        if (vg >= 0 && vg < 257 && ug >= 0 && ug < 512)
            val = XT[(((size_t)n * 16 + c) * 257 + vg) * 512 + ug];
        Xs[l] = val;
    }
    __syncthreads();

    int lane = tid & 63;
    int wv = __builtin_amdgcn_readfirstlane(tid >> 6);
    int o0 = wv * 4;

    float2 acc[2][4];  // [vv][oo]
#pragma unroll
    for (int oo = 0; oo < 4; ++oo) {
        float2 bv = make_float2(br[o0 + oo], bi[o0 + oo]);
        acc[0][oo] = bv;
        acc[1][oo] = bv;
    }

    for (int c = 0; c < 16; ++c) {
        float2 xv[4][3];
#pragma unroll
        for (int dvr = 0; dvr < 4; ++dvr) {
            const float2* row = &Xs[(c * 4 + dvr) * 66];
            xv[dvr][0] = row[lane];
            xv[dvr][1] = row[lane + 1];
            xv[dvr][2] = row[lane + 2];
        }
#pragma unroll
        for (int oo = 0; oo < 4; ++oo) {
            const float* wrp = wr + ((size_t)(c * 16 + o0 + oo)) * 9;
            const float* wip = wi + ((size_t)(c * 16 + o0 + oo)) * 9;
            float wre[9], wim[9];
#pragma unroll
            for (int t = 0; t < 9; ++t) { wre[t] = wrp[t]; wim[t] = wip[t]; }
#pragma unroll
            for (int kw = 0; kw < 3; ++kw) {
                // output v0+vv needs X halo row vg = v0+vv-(kw-1) -> dvr = vv+2-kw
#pragma unroll
                for (int kh = 0; kh < 3; ++kh) {
                    int t = kh * 3 + kw;
                    int xj = 2 - kh;
                    float2 w = make_float2(wre[t], wim[t]);
                    cmac(acc[0][oo], w, xv[2 - kw][xj]);
                    cmac(acc[1][oo], w, xv[3 - kw][xj]);
                }
            }
        }
    }

#pragma unroll
    for (int oo = 0; oo < 4; ++oo) {
#pragma unroll
        for (int vv = 0; vv < 2; ++vv) {
            int v = v0 + vv;
            if (v < 257)
                YT[(((size_t)n * 16 + o0 + oo) * 257 + v) * 512 + u0 + lane] =
                    acc[vv][oo];
        }
    }
}

// K4: inverse FFT along u (scale 1/512) for 4 columns. (round-3 layout.)
__global__ __launch_bounds__(256) void k_col_ifft(const float2* __restrict__ YT,
                                                  float2* __restrict__ ZT) {
    __shared__ float2 b0[4 * CSTRIDE], b1[4 * CSTRIDE], tbl[128];
    int tid = threadIdx.x;
    int no = blockIdx.x / 65;
    int v0 = (blockIdx.x % 65) * 4;
    build_tbl128(tbl, tid);
#pragma unroll
    for (int k = 0; k < 4; ++k) {
        int v = v0 + k;
        const float2* src = YT + ((size_t)no * 257 + (v < 257 ? v : 256)) * 512;
        b0[k * CSTRIDE + FI(tid)]       = src[tid];
        b0[k * CSTRIDE + FI(tid + 256)] = src[tid + 256];
    }
    __syncthreads();
    float2* res = fft512_r4<4>(b0, b1, tbl, tid, true);
    const float sc = 1.0f / 512.0f;
#pragma unroll
    for (int k = 0; k < 4; ++k) {
        int v = v0 + k;
        if (v < 257) {
            float2* dst = ZT + ((size_t)no * 257 + v) * 512;
            float2 r0 = res[k * CSTRIDE + FI(tid)];
            float2 r1 = res[k * CSTRIDE + FI(tid + 256)];
            dst[tid]       = make_float2(r0.x * sc, r0.y * sc);
            dst[tid + 256] = make_float2(r1.x * sc, r1.y * sc);
        }
    }
}

// K5: irfft along v for 4 rows h0..h0+3 (imag of DC/Nyquist ignored).
// XCD-chunk swizzled so h-group neighbors (sharing ZT lines) co-locate.
__global__ __launch_bounds__(256) void k_row_irfft(const float2* __restrict__ ZT,
                                                   float* __restrict__ out) {
    __shared__ float2 b0[4 * CSTRIDE], b1[4 * CSTRIDE], tbl[128];
    int tid = threadIdx.x;
    int l = xcd_remap(blockIdx.x, 2048);  // grid = 16384
    int no = l >> 7;
    int h0 = (l & 127) * 4;
    build_tbl128(tbl, tid);
#pragma unroll
    for (int i = 0; i < 5; ++i) {
        int e = tid + 256 * i;
        if (e < 1028) {
            int k = e & 3, vv = e >> 2;
            float2 val = ZT[((size_t)no * 257 + vv) * 512 + h0 + k];
            if (vv == 0 || vv == 256) val.y = 0.0f;
            b0[k * CSTRIDE + FI(vv)] = val;
        }
    }
    __syncthreads();
#pragma unroll
    for (int i = 0; i < 4; ++i) {
        int e = tid + 256 * i;
        if (e < 1020) {
            int k = e & 3, vv = 257 + (e >> 2);
            float2 s = b0[k * CSTRIDE + FI(512 - vv)];
            b0[k * CSTRIDE + FI(vv)] = make_float2(s.x, -s.y);
        }
    }
    __syncthreads();
    float2* res = fft512_r4<4>(b0, b1, tbl, tid, true);
    const float sc = 1.0f / 512.0f;
#pragma unroll
    for (int k = 0; k < 4; ++k) {
        float* dst = out + ((size_t)no * 512 + h0 + k) * 512;
        dst[tid]       = res[k * CSTRIDE + FI(tid)].x * sc;
        dst[tid + 256] = res[k * CSTRIDE + FI(tid + 256)].x * sc;
    }
}

extern "C" void kernel_launch(void* const* d_in, const int* in_sizes, int n_in,
                              void* d_out, int out_size, void* d_ws, size_t ws_size,
                              hipStream_t stream) {
    const float* x  = (const float*)d_in[0];
    const float* wr = (const float*)d_in[1];
    const float* wi = (const float*)d_in[2];
    const float* br = (const float*)d_in[3];
    const float* bi = (const float*)d_in[4];
    float* out = (float*)d_out;

    const size_t bufElems = (size_t)128 * 257 * 512;  // complex elements
    float2* A = (float2*)d_ws;
    float2* B = A + bufElems;

    k_row_rfft<<<128 * 128, 256, 0, stream>>>(x, A);                 // x -> G (A)
    k_col_fft<<<128 * 65, 256, 0, stream>>>(A, B);                   // G -> XT (B)
    k_conv<<<8 * 129 * 8, 256, 0, stream>>>(B, A, wr, wi, br, bi);   // XT -> YT (A)
    k_col_ifft<<<128 * 65, 256, 0, stream>>>(A, B);                  // YT -> ZT (B)
    k_row_irfft<<<128 * 128, 256, 0, stream>>>(B, out);              // ZT -> out
}